// Round 13
// baseline (116.358 us; speedup 1.0000x reference)
//
#include <hip/hip_runtime.h>

#define T_DIM 256
#define C_DIM 384
#define H_DIM 64

typedef __attribute__((ext_vector_type(4))) float f32x4;
typedef __attribute__((ext_vector_type(8))) short bf16x8;
typedef unsigned short u16;

// fp32 -> bf16 round-to-nearest-even (finite inputs)
__device__ __forceinline__ u16 f2b(float f) {
  unsigned u = __float_as_uint(f);
  u = (u + 0x7FFFu + ((u >> 16) & 1u)) >> 16;
  return (u16)u;
}
// packed f32x2 -> bf16x2: lo word = bf16(a), hi word = bf16(b)  (HW-verified R7/R8)
__device__ __forceinline__ unsigned pkbf(float a, float b) {
  unsigned r;
  asm("v_cvt_pk_bf16_f32 %0, %1, %2" : "=v"(r) : "v"(a), "v"(b));
  return r;
}

// Swizzled element offsets (u16 units). Writes and reads share the permutation.
__device__ __forceinline__ int sw64(int r, int c)  { return r * 64  + (c ^ ((r & 7) << 3)); }
__device__ __forceinline__ int sw256(int h, int t) { return h * 256 + (t ^ ((h & 7) << 3)); }
__device__ __forceinline__ int sw32(int r, int c)  { return r * 32  + (c ^ (((r >> 1) & 3) << 3)); }

// ---------- kernel 0: W^T precompute -> d_ws ----------
// wt[192][384] bf16: rows 0-63 = Wq^T, 64-127 = Wk^T, 128-191 = Wv^T (k-contiguous).
// Rewritten in full every call (deterministic; no cross-call state).
__global__ void wtrans_k(const float* __restrict__ Wq, const float* __restrict__ Wk,
                         const float* __restrict__ Wv, u16* __restrict__ wt)
{
  int blk = blockIdx.x;                       // 0..287 (96 per segment)
  int seg = blk / 96;                         // 0:Q 1:K 2:V
  int id  = (blk % 96) * 256 + threadIdx.x;   // 0..24575
  int h = id & 63, k = id >> 6;               // h 0..63, k 0..383
  const float* W = (seg == 0) ? Wq : (seg == 1) ? Wk : Wv;
  wt[(seg * 64 + h) * C_DIM + k] = f2b(W[k * H_DIM + h]);
}

// ---------- main kernel ----------
// One block per batch. 512 threads = 8 waves. LDS = 64 KB -> 2 blocks/CU.
// Phase 1 (restructured this round): QKV GEMM with
//   - B-fragments DIRECT from global wt (L2-resident 147 KB, 16B/lane contiguous)
//   - x staged WAVE-LOCALLY (each wave stages only its own 32 rows), double-
//     buffered across chunk parity -> only a wave-local lgkmcnt fence, NO
//     __syncthreads in the whole 12-chunk loop (was 24 barriers in R12).
// Handoff + Phase 2: R12-proven verbatim (swapped-operand flash attention).
__global__ __launch_bounds__(512, 2)
void head_fused(const float* __restrict__ x,
                const u16*   __restrict__ wt,
                float* __restrict__ out)
{
  __shared__ u16 sh[32768];   // 64 KB union:
  // phase 1: xsA = sh[0..8192) [256][32] sw32 (even chunks); xsB = sh[8192..16384) (odd)
  // handoff: per-wave Q slab at sh[wv*2048 .. +2048) [32][64] sw64
  // phase 2: ks = sh[0..16384) [256][64] sw64; vT = sh[16384..32768) [64][256] sw256
  u16* xsA = sh;
  u16* xsB = sh + 8192;
  u16* ks  = sh;
  u16* vT  = sh + 16384;

  const int tid  = threadIdx.x;
  const int wv   = tid >> 6;
  const int lane = tid & 63;
  const int g    = lane >> 4;
  const int lr   = lane & 15;
  const int b    = blockIdx.x;

  const float* xb = x + (size_t)b * (T_DIM * C_DIM);

  // ---------------- Phase 1: QKV projection (barrier-free) ----------------
  // Wave-local staging: lane stages row 32wv + (lane&31), cols 16*(lane>>5)..+15.
  const int srow = wv * 32 + (lane & 31);
  const int scg  = (lane >> 5) * 16;          // 0 or 16
  const float* xsrc = xb + srow * C_DIM + scg;

  // B-fragment base: wt[(nj*16+lr)*384 + kt*32 + g*8], 16B contiguous per lane
  const u16* wb = wt + (size_t)lr * C_DIM + g * 8;

  f32x4 acc[2][12];
#pragma unroll
  for (int mi = 0; mi < 2; ++mi)
#pragma unroll
    for (int nj = 0; nj < 12; ++nj)
      acc[mi][nj] = (f32x4){0.f, 0.f, 0.f, 0.f};

  // prefetch chunk 0 (16 floats = this lane's staging slice)
  f32x4 px[4];
#pragma unroll
  for (int i = 0; i < 4; ++i)
    px[i] = *reinterpret_cast<const f32x4*>(xsrc + i * 4);

  for (int kt = 0; kt < 12; ++kt) {
    u16* xs = (kt & 1) ? xsB : xsA;
    // convert + store this lane's 16 elems (two 16B stores, sw32 keeps 8-blocks contiguous)
    uint4 w0, w1;
    w0.x = pkbf(px[0][0], px[0][1]);  w0.y = pkbf(px[0][2], px[0][3]);
    w0.z = pkbf(px[1][0], px[1][1]);  w0.w = pkbf(px[1][2], px[1][3]);
    w1.x = pkbf(px[2][0], px[2][1]);  w1.y = pkbf(px[2][2], px[2][3]);
    w1.z = pkbf(px[3][0], px[3][1]);  w1.w = pkbf(px[3][2], px[3][3]);
    *reinterpret_cast<uint4*>(&xs[sw32(srow, scg)])     = w0;
    *reinterpret_cast<uint4*>(&xs[sw32(srow, scg + 8)]) = w1;
    // prefetch next chunk (independent of LDS; hides under MFMA)
    if (kt < 11) {
      const float* p = xsrc + (kt + 1) * 32;
#pragma unroll
      for (int i = 0; i < 4; ++i)
        px[i] = *reinterpret_cast<const f32x4*>(p + i * 4);
    }
    // wave-local fence: own stores visible to own reads (rows are wave-private)
    asm volatile("s_waitcnt lgkmcnt(0)" ::: "memory");

    // A-fragments from own rows
    bf16x8 afr[2];
#pragma unroll
    for (int mi = 0; mi < 2; ++mi)
      afr[mi] = *reinterpret_cast<const bf16x8*>(&xs[sw32(wv * 32 + mi * 16 + lr, g * 8)]);
    // B-fragments direct from global wt (L2-hot), 24 MFMA
#pragma unroll
    for (int nj = 0; nj < 12; ++nj) {
      bf16x8 bfr = *reinterpret_cast<const bf16x8*>(wb + nj * (16 * C_DIM) + kt * 32);
      acc[0][nj] = __builtin_amdgcn_mfma_f32_16x16x32_bf16(afr[0], bfr, acc[0][nj], 0, 0, 0);
      acc[1][nj] = __builtin_amdgcn_mfma_f32_16x16x32_bf16(afr[1], bfr, acc[1][nj], 0, 0, 0);
    }
  }

  // ---------------- Handoff (R12-proven) ----------------
  __syncthreads();   // all waves done with xsA/xsB; staging region now dead

  // (1) own Q rows D->slab (acc nj 0..3 hold Q[32wv + 16mi + 4g+e][16nj+lr])
  u16* slab = sh + wv * 2048;   // [32][64] sw64, wave-private
#pragma unroll
  for (int mi = 0; mi < 2; ++mi)
#pragma unroll
    for (int nj = 0; nj < 4; ++nj)
#pragma unroll
      for (int e = 0; e < 4; ++e)
        slab[sw64(mi * 16 + g * 4 + e, nj * 16 + lr)] = f2b(acc[mi][nj][e]);
  asm volatile("s_waitcnt lgkmcnt(0)" ::: "memory");

  // (2) read Q as B-fragments: qf[mi][kb][e] = Q[32wv+16mi+lr][32kb+8g+e]
  bf16x8 qf[2][2];
#pragma unroll
  for (int mi = 0; mi < 2; ++mi)
#pragma unroll
    for (int kb = 0; kb < 2; ++kb)
      qf[mi][kb] = *reinterpret_cast<const bf16x8*>(&slab[sw64(mi * 16 + lr, kb * 32 + g * 8)]);
  __syncthreads();   // all slab reads done before K/V scatter overwrites the region

  // (3) scatter K,V fragments (acc nj 4..11) into ks/vT
#pragma unroll
  for (int mi = 0; mi < 2; ++mi)
#pragma unroll
    for (int nj = 4; nj < 12; ++nj)
#pragma unroll
      for (int e = 0; e < 4; ++e) {
        int r = wv * 32 + mi * 16 + g * 4 + e;
        int n = nj * 16 + lr;
        u16 val = f2b(acc[mi][nj][e]);
        if (n < 128) ks[sw64(r, n - 64)] = val;
        else         vT[sw256(n - 128, r)] = val;
      }
  __syncthreads();

  // ---------------- Phase 2: swapped-operand causal flash attention (R12-proven) ----------------
  const int r0   = wv * 32;
  const int jmax = wv >> 1;

  f32x4 o[2][4];              // O D-layout: row q-local = 16mi+4g+e, col h = 16nh+lr
  float m_run[2], l_run[2];   // per-lane stats for q = r0 + 16mi + lr
#pragma unroll
  for (int mi = 0; mi < 2; ++mi) {
    m_run[mi] = -__builtin_inff();
    l_run[mi] = 0.f;
#pragma unroll
    for (int nh = 0; nh < 4; ++nh) o[mi][nh] = (f32x4){0.f, 0.f, 0.f, 0.f};
  }

  for (int j = 0; j <= jmax; ++j) {
    // S^T tile: sT[mi][ni][e] = S[q = r0+16mi+lr][kv = 64j+16ni+4g+e]
    f32x4 sT[2][4];
#pragma unroll
    for (int mi = 0; mi < 2; ++mi)
#pragma unroll
      for (int ni = 0; ni < 4; ++ni)
        sT[mi][ni] = (f32x4){0.f, 0.f, 0.f, 0.f};
#pragma unroll
    for (int kb = 0; kb < 2; ++kb) {
#pragma unroll
      for (int ni = 0; ni < 4; ++ni) {
        bf16x8 kf = *reinterpret_cast<const bf16x8*>(&ks[sw64(j * 64 + ni * 16 + lr, kb * 32 + g * 8)]);
#pragma unroll
        for (int mi = 0; mi < 2; ++mi)
          sT[mi][ni] = __builtin_amdgcn_mfma_f32_16x16x32_bf16(kf, qf[mi][kb], sT[mi][ni], 0, 0, 0);
      }
    }

    // scale + causal mask + per-row (=per-lane-q) softmax
#pragma unroll
    for (int mi = 0; mi < 2; ++mi) {
      const int q = r0 + mi * 16 + lr;
      float pm = -__builtin_inff();
#pragma unroll
      for (int ni = 0; ni < 4; ++ni)
#pragma unroll
        for (int e = 0; e < 4; ++e) {
          float v = sT[mi][ni][e] * 0.125f;
          int kv = j * 64 + ni * 16 + g * 4 + e;
          v = (kv > q) ? -__builtin_inff() : v;
          sT[mi][ni][e] = v;
          pm = fmaxf(pm, v);
        }
      pm = fmaxf(pm, __shfl_xor(pm, 16));
      pm = fmaxf(pm, __shfl_xor(pm, 32));

      float mn = fmaxf(m_run[mi], pm);
      float alpha = __expf(m_run[mi] - mn);   // first tile: exp(-inf)=0
      m_run[mi] = mn;
      float rs = 0.f;
#pragma unroll
      for (int ni = 0; ni < 4; ++ni)
#pragma unroll
        for (int e = 0; e < 4; ++e) {
          float p = __expf(sT[mi][ni][e] - mn);  // masked: exp(-inf)=0
          sT[mi][ni][e] = p;
          rs += p;
        }
      rs += __shfl_xor(rs, 16);
      rs += __shfl_xor(rs, 32);
      l_run[mi] = l_run[mi] * alpha + rs;

      // rescale O (alpha for q-row 16mi+4g+e lives at lane lr' = 4g+e)
#pragma unroll
      for (int e = 0; e < 4; ++e) {
        float am = __shfl(alpha, g * 4 + e);
#pragma unroll
        for (int nh = 0; nh < 4; ++nh) o[mi][nh][e] *= am;
      }
    }

    // P D->A transpose via g-group exchange (no LDS)
    union PA { unsigned w[4]; bf16x8 v; };
    PA pa[2][2];
#pragma unroll
    for (int mi = 0; mi < 2; ++mi) {
      unsigned pk[4][2];
#pragma unroll
      for (int ni = 0; ni < 4; ++ni) {
        pk[ni][0] = pkbf(sT[mi][ni][0], sT[mi][ni][1]);  // kv {16ni+4g+0, +1}
        pk[ni][1] = pkbf(sT[mi][ni][2], sT[mi][ni][3]);  // kv {16ni+4g+2, +3}
      }
#pragma unroll
      for (int kb = 0; kb < 2; ++kb)
#pragma unroll
        for (int w = 0; w < 4; ++w) {
          int sl = ((2 * g + (w >> 1)) & 3) * 16 + lr;   // source lane
          unsigned lo = __shfl(pk[2 * kb + 0][w & 1], sl);
          unsigned hi = __shfl(pk[2 * kb + 1][w & 1], sl);
          pa[mi][kb].w[w] = (g >= 2) ? hi : lo;
        }
    }

    // O += P @ V_tile
#pragma unroll
    for (int kb = 0; kb < 2; ++kb) {
#pragma unroll
      for (int nh = 0; nh < 4; ++nh) {
        bf16x8 vf = *reinterpret_cast<const bf16x8*>(&vT[sw256(nh * 16 + lr, j * 64 + kb * 32 + g * 8)]);
#pragma unroll
        for (int mi = 0; mi < 2; ++mi)
          o[mi][nh] = __builtin_amdgcn_mfma_f32_16x16x32_bf16(pa[mi][kb].v, vf, o[mi][nh], 0, 0, 0);
      }
    }
  }

  // epilogue: normalize and store fp32 (l for q-row 16mi+4g+e lives at lane 4g+e)
  float* ob = out + (size_t)b * (T_DIM * H_DIM);
#pragma unroll
  for (int mi = 0; mi < 2; ++mi) {
    float linv[4];
#pragma unroll
    for (int e = 0; e < 4; ++e)
      linv[e] = 1.f / __shfl(l_run[mi], g * 4 + e);
#pragma unroll
    for (int nh = 0; nh < 4; ++nh)
#pragma unroll
      for (int e = 0; e < 4; ++e) {
        int r = r0 + mi * 16 + g * 4 + e;
        int h = nh * 16 + lr;
        ob[r * H_DIM + h] = o[mi][nh][e] * linv[e];
      }
  }
}

extern "C" void kernel_launch(void* const* d_in, const int* in_sizes, int n_in,
                              void* d_out, int out_size, void* d_ws, size_t ws_size,
                              hipStream_t stream) {
  const float* x  = (const float*)d_in[0];
  const float* Wk = (const float*)d_in[1];
  const float* Wq = (const float*)d_in[2];
  const float* Wv = (const float*)d_in[3];
  float* out = (float*)d_out;
  u16* wt = (u16*)d_ws;                       // 192*384*2 = 147456 B
  int B = in_sizes[0] / (T_DIM * C_DIM);      // 512

  wtrans_k<<<dim3(288), dim3(256), 0, stream>>>(Wq, Wk, Wv, wt);
  head_fused<<<dim3(B), dim3(512), 0, stream>>>(x, wt, out);
}

// Round 14
// 69.842 us; speedup vs baseline: 1.6660x; 1.6660x over previous
//
#include <hip/hip_runtime.h>

#define T_DIM 256
#define C_DIM 384
#define H_DIM 64

typedef __attribute__((ext_vector_type(4))) float f32x4;
typedef __attribute__((ext_vector_type(8))) short bf16x8;
typedef unsigned short u16;

// fp32 -> bf16 round-to-nearest-even (finite inputs)
__device__ __forceinline__ u16 f2b(float f) {
  unsigned u = __float_as_uint(f);
  u = (u + 0x7FFFu + ((u >> 16) & 1u)) >> 16;
  return (u16)u;
}
// packed f32x2 -> bf16x2: lo word = bf16(a), hi word = bf16(b)  (HW-verified R7/R8)
__device__ __forceinline__ unsigned pkbf(float a, float b) {
  unsigned r;
  asm("v_cvt_pk_bf16_f32 %0, %1, %2" : "=v"(r) : "v"(a), "v"(b));
  return r;
}

// Swizzled element offsets (u16 units). Writes and reads share the permutation.
__device__ __forceinline__ int sw64(int r, int c)  { return r * 64  + (c ^ ((r & 7) << 3)); }
__device__ __forceinline__ int sw256(int h, int t) { return h * 256 + (t ^ ((h & 7) << 3)); }
__device__ __forceinline__ int sw32(int r, int c)  { return r * 32  + (c ^ (((r >> 1) & 3) << 3)); }

// One block per batch. 512 threads = 8 waves. LDS = 64 KB -> 2 blocks/CU.
// R12-proven structure (62.8 us). Single change this round: x-prefetch depth
// 1 -> 2 (px[2][4], chunk kt+2 issued at kt). R13 proved the chunk loop is
// LATENCY-bound (not barrier-bound): staging stores stalled ~600cy on the
// previous chunk's HBM loads. Depth-2 gives ~2 MFMA sections + 2 barriers of
// slack and doubles in-flight HBM bytes per CU (64->128 B/lane).
// B-fragments stay in LDS (R13 proved global-direct B is latency-poison).
// Phase 1: QKV = x_b @ [Wq|Wk|Wv], M=256 N=192 K=384, K-step 32.
// Handoff: per-wave Q D->B transpose via private slab in dead staging LDS.
// Phase 2: swapped-operand flash attention (q lane-local; P transpose via shfl).
__global__ __launch_bounds__(512, 2)
void head_fused(const float* __restrict__ x,
                const float* __restrict__ Wk,
                const float* __restrict__ Wq,
                const float* __restrict__ Wv,
                float* __restrict__ out)
{
  __shared__ u16 sh[32768];   // 64 KB union:
  // phase 1: xs = sh[0..8192) [256][32] sw32; wsT = sh[8192..14336) [192][32] sw32
  // handoff: per-wave Q slab at sh[wv*2048 .. +2048) [32][64] sw64
  // phase 2: ks = sh[0..16384) [256][64] sw64; vT = sh[16384..32768) [64][256] sw256
  u16* xs  = sh;
  u16* wsT = sh + 8192;
  u16* ks  = sh;
  u16* vT  = sh + 16384;

  const int tid  = threadIdx.x;
  const int wv   = tid >> 6;
  const int lane = tid & 63;
  const int g    = lane >> 4;
  const int lr   = lane & 15;
  const int b    = blockIdx.x;

  const float* xb = x + (size_t)b * (T_DIM * C_DIM);

  // ---------------- Phase 1: QKV projection ----------------
  int xr[4], xc[4];
#pragma unroll
  for (int it = 0; it < 4; ++it) {
    int idx = tid + it * 512;
    xr[it] = idx >> 3;
    xc[it] = (idx & 7) * 4;
  }
  int wrow[3], wcc[3];
  const float* wsrc[3];
#pragma unroll
  for (int it = 0; it < 3; ++it) {
    int idx = tid + it * 512;          // 0..1535
    int q   = idx >> 5;                // row-quad 0..47
    int cc  = idx & 31;                // col 0..31
    int seg = q >> 4;                  // 0:Q 1:K 2:V
    int hq  = q & 15;
    wrow[it] = seg * 64 + hq * 4;
    wcc[it]  = cc;
    wsrc[it] = ((seg == 0) ? Wq : (seg == 1) ? Wk : Wv) + hq * 4;
  }

  f32x4 acc[2][12];
#pragma unroll
  for (int mi = 0; mi < 2; ++mi)
#pragma unroll
    for (int nj = 0; nj < 12; ++nj)
      acc[mi][nj] = (f32x4){0.f, 0.f, 0.f, 0.f};

  // x prefetch DEPTH 2: px[parity][4]; W prefetch depth 1 (L2-hot)
  f32x4 px[2][4], pwv[3];
#pragma unroll
  for (int c = 0; c < 2; ++c)
#pragma unroll
    for (int it = 0; it < 4; ++it)
      px[c][it] = *reinterpret_cast<const f32x4*>(xb + xr[it] * C_DIM + c * 32 + xc[it]);
#pragma unroll
  for (int it = 0; it < 3; ++it)
    pwv[it] = *reinterpret_cast<const f32x4*>(wsrc[it] + wcc[it] * H_DIM);

  for (int kt = 0; kt < 12; ++kt) {
    const int c = kt & 1;
    __syncthreads();   // previous iteration's fragment reads done
    // store chunk kt from px[c]
#pragma unroll
    for (int it = 0; it < 4; ++it) {
      uint2 pv;
      pv.x = pkbf(px[c][it][0], px[c][it][1]);
      pv.y = pkbf(px[c][it][2], px[c][it][3]);
      *reinterpret_cast<uint2*>(&xs[sw32(xr[it], xc[it])]) = pv;
    }
#pragma unroll
    for (int it = 0; it < 3; ++it) {
      wsT[sw32(wrow[it] + 0, wcc[it])] = f2b(pwv[it][0]);
      wsT[sw32(wrow[it] + 1, wcc[it])] = f2b(pwv[it][1]);
      wsT[sw32(wrow[it] + 2, wcc[it])] = f2b(pwv[it][2]);
      wsT[sw32(wrow[it] + 3, wcc[it])] = f2b(pwv[it][3]);
    }
    // issue x loads for chunk kt+2 into freed parity slot; W for kt+1
    if (kt < 10) {
      int kk = (kt + 2) * 32;
#pragma unroll
      for (int it = 0; it < 4; ++it)
        px[c][it] = *reinterpret_cast<const f32x4*>(xb + xr[it] * C_DIM + kk + xc[it]);
    }
    if (kt < 11) {
      int kk = (kt + 1) * 32;
#pragma unroll
      for (int it = 0; it < 3; ++it)
        pwv[it] = *reinterpret_cast<const f32x4*>(wsrc[it] + (kk + wcc[it]) * H_DIM);
    }
    __syncthreads();

    bf16x8 afr[2];
#pragma unroll
    for (int mi = 0; mi < 2; ++mi)
      afr[mi] = *reinterpret_cast<const bf16x8*>(&xs[sw32(wv * 32 + mi * 16 + lr, g * 8)]);
#pragma unroll
    for (int nj = 0; nj < 12; ++nj) {
      bf16x8 bfr = *reinterpret_cast<const bf16x8*>(&wsT[sw32(nj * 16 + lr, g * 8)]);
#pragma unroll
      for (int mi = 0; mi < 2; ++mi)
        acc[mi][nj] = __builtin_amdgcn_mfma_f32_16x16x32_bf16(afr[mi], bfr, acc[mi][nj], 0, 0, 0);
    }
  }

  // ---------------- Handoff (R12-proven) ----------------
  __syncthreads();   // all waves' staging reads done; staging region now dead

  // (1) own Q rows D->slab (acc nj 0..3 hold Q[32wv + 16mi + 4g+e][16nj+lr])
  u16* slab = sh + wv * 2048;   // [32][64] sw64, wave-private
#pragma unroll
  for (int mi = 0; mi < 2; ++mi)
#pragma unroll
    for (int nj = 0; nj < 4; ++nj)
#pragma unroll
      for (int e = 0; e < 4; ++e)
        slab[sw64(mi * 16 + g * 4 + e, nj * 16 + lr)] = f2b(acc[mi][nj][e]);
  asm volatile("s_waitcnt lgkmcnt(0)" ::: "memory");

  // (2) read Q as B-fragments: qf[mi][kb][e] = Q[32wv+16mi+lr][32kb+8g+e]
  bf16x8 qf[2][2];
#pragma unroll
  for (int mi = 0; mi < 2; ++mi)
#pragma unroll
    for (int kb = 0; kb < 2; ++kb)
      qf[mi][kb] = *reinterpret_cast<const bf16x8*>(&slab[sw64(mi * 16 + lr, kb * 32 + g * 8)]);
  __syncthreads();   // all slab reads done before K/V scatter overwrites the region

  // (3) scatter K,V fragments (acc nj 4..11) into ks/vT
#pragma unroll
  for (int mi = 0; mi < 2; ++mi)
#pragma unroll
    for (int nj = 4; nj < 12; ++nj)
#pragma unroll
      for (int e = 0; e < 4; ++e) {
        int r = wv * 32 + mi * 16 + g * 4 + e;
        int n = nj * 16 + lr;
        u16 val = f2b(acc[mi][nj][e]);
        if (n < 128) ks[sw64(r, n - 64)] = val;
        else         vT[sw256(n - 128, r)] = val;
      }
  __syncthreads();

  // ---------------- Phase 2: swapped-operand causal flash attention (R12-proven) ----------------
  const int r0   = wv * 32;
  const int jmax = wv >> 1;

  f32x4 o[2][4];              // O D-layout: row q-local = 16mi+4g+e, col h = 16nh+lr
  float m_run[2], l_run[2];   // per-lane stats for q = r0 + 16mi + lr
#pragma unroll
  for (int mi = 0; mi < 2; ++mi) {
    m_run[mi] = -__builtin_inff();
    l_run[mi] = 0.f;
#pragma unroll
    for (int nh = 0; nh < 4; ++nh) o[mi][nh] = (f32x4){0.f, 0.f, 0.f, 0.f};
  }

  for (int j = 0; j <= jmax; ++j) {
    // S^T tile: sT[mi][ni][e] = S[q = r0+16mi+lr][kv = 64j+16ni+4g+e]
    f32x4 sT[2][4];
#pragma unroll
    for (int mi = 0; mi < 2; ++mi)
#pragma unroll
      for (int ni = 0; ni < 4; ++ni)
        sT[mi][ni] = (f32x4){0.f, 0.f, 0.f, 0.f};
#pragma unroll
    for (int kb = 0; kb < 2; ++kb) {
#pragma unroll
      for (int ni = 0; ni < 4; ++ni) {
        bf16x8 kf = *reinterpret_cast<const bf16x8*>(&ks[sw64(j * 64 + ni * 16 + lr, kb * 32 + g * 8)]);
#pragma unroll
        for (int mi = 0; mi < 2; ++mi)
          sT[mi][ni] = __builtin_amdgcn_mfma_f32_16x16x32_bf16(kf, qf[mi][kb], sT[mi][ni], 0, 0, 0);
      }
    }

    // scale + causal mask + per-row (=per-lane-q) softmax
#pragma unroll
    for (int mi = 0; mi < 2; ++mi) {
      const int q = r0 + mi * 16 + lr;
      float pm = -__builtin_inff();
#pragma unroll
      for (int ni = 0; ni < 4; ++ni)
#pragma unroll
        for (int e = 0; e < 4; ++e) {
          float v = sT[mi][ni][e] * 0.125f;
          int kv = j * 64 + ni * 16 + g * 4 + e;
          v = (kv > q) ? -__builtin_inff() : v;
          sT[mi][ni][e] = v;
          pm = fmaxf(pm, v);
        }
      pm = fmaxf(pm, __shfl_xor(pm, 16));
      pm = fmaxf(pm, __shfl_xor(pm, 32));

      float mn = fmaxf(m_run[mi], pm);
      float alpha = __expf(m_run[mi] - mn);   // first tile: exp(-inf)=0
      m_run[mi] = mn;
      float rs = 0.f;
#pragma unroll
      for (int ni = 0; ni < 4; ++ni)
#pragma unroll
        for (int e = 0; e < 4; ++e) {
          float p = __expf(sT[mi][ni][e] - mn);  // masked: exp(-inf)=0
          sT[mi][ni][e] = p;
          rs += p;
        }
      rs += __shfl_xor(rs, 16);
      rs += __shfl_xor(rs, 32);
      l_run[mi] = l_run[mi] * alpha + rs;

      // rescale O (alpha for q-row 16mi+4g+e lives at lane lr' = 4g+e)
#pragma unroll
      for (int e = 0; e < 4; ++e) {
        float am = __shfl(alpha, g * 4 + e);
#pragma unroll
        for (int nh = 0; nh < 4; ++nh) o[mi][nh][e] *= am;
      }
    }

    // P D->A transpose via g-group exchange (no LDS)
    union PA { unsigned w[4]; bf16x8 v; };
    PA pa[2][2];
#pragma unroll
    for (int mi = 0; mi < 2; ++mi) {
      unsigned pk[4][2];
#pragma unroll
      for (int ni = 0; ni < 4; ++ni) {
        pk[ni][0] = pkbf(sT[mi][ni][0], sT[mi][ni][1]);  // kv {16ni+4g+0, +1}
        pk[ni][1] = pkbf(sT[mi][ni][2], sT[mi][ni][3]);  // kv {16ni+4g+2, +3}
      }
#pragma unroll
      for (int kb = 0; kb < 2; ++kb)
#pragma unroll
        for (int w = 0; w < 4; ++w) {
          int sl = ((2 * g + (w >> 1)) & 3) * 16 + lr;   // source lane
          unsigned lo = __shfl(pk[2 * kb + 0][w & 1], sl);
          unsigned hi = __shfl(pk[2 * kb + 1][w & 1], sl);
          pa[mi][kb].w[w] = (g >= 2) ? hi : lo;
        }
    }

    // O += P @ V_tile
#pragma unroll
    for (int kb = 0; kb < 2; ++kb) {
#pragma unroll
      for (int nh = 0; nh < 4; ++nh) {
        bf16x8 vf = *reinterpret_cast<const bf16x8*>(&vT[sw256(nh * 16 + lr, j * 64 + kb * 32 + g * 8)]);
#pragma unroll
        for (int mi = 0; mi < 2; ++mi)
          o[mi][nh] = __builtin_amdgcn_mfma_f32_16x16x32_bf16(pa[mi][kb].v, vf, o[mi][nh], 0, 0, 0);
      }
    }
  }

  // epilogue: normalize and store fp32 (l for q-row 16mi+4g+e lives at lane 4g+e)
  float* ob = out + (size_t)b * (T_DIM * H_DIM);
#pragma unroll
  for (int mi = 0; mi < 2; ++mi) {
    float linv[4];
#pragma unroll
    for (int e = 0; e < 4; ++e)
      linv[e] = 1.f / __shfl(l_run[mi], g * 4 + e);
#pragma unroll
    for (int nh = 0; nh < 4; ++nh)
#pragma unroll
      for (int e = 0; e < 4; ++e) {
        int r = r0 + mi * 16 + g * 4 + e;
        int h = nh * 16 + lr;
        ob[r * H_DIM + h] = o[mi][nh][e] * linv[e];
      }
  }
}

extern "C" void kernel_launch(void* const* d_in, const int* in_sizes, int n_in,
                              void* d_out, int out_size, void* d_ws, size_t ws_size,
                              hipStream_t stream) {
  const float* x  = (const float*)d_in[0];
  const float* Wk = (const float*)d_in[1];
  const float* Wq = (const float*)d_in[2];
  const float* Wv = (const float*)d_in[3];
  float* out = (float*)d_out;
  int B = in_sizes[0] / (T_DIM * C_DIM);   // 512
  head_fused<<<dim3(B), dim3(512), 0, stream>>>(x, Wk, Wq, Wv, out);
}